// Round 11
// baseline (2411.366 us; speedup 1.0000x reference)
//
#include <hip/hip_runtime.h>
#include <math.h>

// ---------------- problem constants ----------------
constexpr int Bn = 1024, Jn = 17, Mn = 34;
constexpr int RJ = Bn * Jn;                 // 17408
constexpr int RM = Bn * Mn;                 // 34816
constexpr size_t SZX = (size_t)RJ * 512;    // floats
constexpr size_t SZM = (size_t)RM * 512;    // floats

typedef __attribute__((ext_vector_type(8))) short bf16x8;
typedef __attribute__((ext_vector_type(4))) float f32x4;
typedef unsigned long long u64;
typedef unsigned short u16;
typedef unsigned int u32;

__device__ __forceinline__ float gelu_f(float x) {
  return 0.5f * x * (1.0f + erff(x * 0.7071067811865475f));
}
__device__ __forceinline__ u16 bf16_rne(float x) {
  u32 u = __float_as_uint(x);
  u += 0x7fffu + ((u >> 16) & 1u);
  return (u16)(u >> 16);
}
__device__ __forceinline__ float bf16_f(u16 h) {
  return __uint_as_float((u32)h << 16);
}

// async global->LDS, 16B per lane; LDS dest = wave-uniform base + lane*16
typedef __attribute__((address_space(1))) const void gas_t;
typedef __attribute__((address_space(3))) void las_t;
__device__ __forceinline__ void gll16(const void* g, void* l) {
  __builtin_amdgcn_global_load_lds((gas_t*)g, (las_t*)l, 16, 0, 0);
}

// ---------------- fused mixer prefix (+optional embed) + weight prep ----------------
template <int EMBED>
__global__ __launch_bounds__(256) void mixer_fused(
    const float* __restrict__ x_in, float* __restrict__ res_out,
    u16* __restrict__ oh, u16* __restrict__ ol,
    const float* __restrict__ g1, const float* __restrict__ b1,
    const float* __restrict__ tw1, const float* __restrict__ tb1,
    const float* __restrict__ tw2, const float* __restrict__ tb2,
    const float* __restrict__ g2, const float* __restrict__ b2,
    const float* __restrict__ W1, const float* __restrict__ W2,
    u16* __restrict__ Th1, u16* __restrict__ Tl1,
    u16* __restrict__ Th2, u16* __restrict__ Tl2,
    const float* __restrict__ joints, const float* __restrict__ inv_tok,
    const float* __restrict__ swg, const float* __restrict__ sbg) {
  __shared__ float xs[17][512];
  __shared__ float stats[17][2];
  const int tid = threadIdx.x;
  const int b = blockIdx.x;
  // weight prep: one element of each weight per thread (1024 blocks x 256 = 262144)
  {
    int gid = b * 256 + tid;
    int k = gid >> 9, n = gid & 511;
    float v = W1[gid];
    u16 h = bf16_rne(v);
    Th1[(size_t)n * 512 + k] = h;
    Tl1[(size_t)n * 512 + k] = bf16_rne(v - bf16_f(h));
    v = W2[gid];
    h = bf16_rne(v);
    Th2[(size_t)n * 512 + k] = h;
    Tl2[(size_t)n * 512 + k] = bf16_rne(v - bf16_f(h));
  }
  if (EMBED) {
    for (int i = tid; i < 17 * 512; i += 256) {
      int j = i >> 9, d = i & 511;
      const float* jp = joints + ((size_t)b * 17 + j) * 3;
      float x = fmaf(jp[0], swg[d], fmaf(jp[1], swg[512 + d], sbg[d]));
      float vis = (jp[2] != 0.0f) ? 1.0f : 0.0f;
      xs[j][d] = x * vis + inv_tok[d] * (1.0f - vis);
    }
  } else {
    const float* px = x_in + (size_t)b * 17 * 512;
    for (int i = tid; i < 17 * 512; i += 256) xs[i >> 9][i & 511] = px[i];
  }
  __syncthreads();
  const int wv = tid >> 6, ln_ = tid & 63;
  // phase A: LN1 stats only
  for (int j = wv; j < 17; j += 4) {
    float v[8];
    float s = 0.0f;
#pragma unroll
    for (int i = 0; i < 8; i++) { v[i] = xs[j][ln_ + 64 * i]; s += v[i]; }
#pragma unroll
    for (int m = 32; m; m >>= 1) s += __shfl_xor(s, m);
    float mean = s * (1.0f / 512.0f);
    float s2 = 0.0f;
#pragma unroll
    for (int i = 0; i < 8; i++) { float t = v[i] - mean; s2 += t * t; }
#pragma unroll
    for (int m = 32; m; m >>= 1) s2 += __shfl_xor(s2, m);
    float rs = 1.0f / sqrtf(s2 * (1.0f / 512.0f) + 1e-5f);
    if (ln_ == 0) { stats[j][0] = mean; stats[j][1] = rs; }
  }
  __syncthreads();
  // phase B: 2 columns/thread; weights via uniform global loads
  {
    const int d0 = tid, d1 = tid + 256;
    float ga = g1[d0], ba = b1[d0];
    float gb = g1[d1], bb2 = b1[d1];
    float t0[17], t1[17], a0[17], a1[17];
#pragma unroll
    for (int j = 0; j < 17; j++) {
      float mj = stats[j][0], rj = stats[j][1];
      t0[j] = (xs[j][d0] - mj) * rj * ga + ba;
      t1[j] = (xs[j][d1] - mj) * rj * gb + bb2;
      a0[j] = 0.0f; a1[j] = 0.0f;
    }
#pragma unroll 1
    for (int k = 0; k < 64; k++) {
      float h0 = tb1[k], h1 = h0;
#pragma unroll
      for (int j = 0; j < 17; j++) {
        float w = tw1[j * 64 + k];
        h0 = fmaf(t0[j], w, h0);
        h1 = fmaf(t1[j], w, h1);
      }
      h0 = gelu_f(h0);
      h1 = gelu_f(h1);
#pragma unroll
      for (int j = 0; j < 17; j++) {
        float w = tw2[k * 17 + j];
        a0[j] = fmaf(h0, w, a0[j]);
        a1[j] = fmaf(h1, w, a1[j]);
      }
    }
#pragma unroll
    for (int j = 0; j < 17; j++) {
      float tb = tb2[j];
      float r0 = xs[j][d0] + a0[j] + tb;
      float r1 = xs[j][d1] + a1[j] + tb;
      xs[j][d0] = r0;
      xs[j][d1] = r1;
      res_out[((size_t)b * 17 + j) * 512 + d0] = r0;
      res_out[((size_t)b * 17 + j) * 512 + d1] = r1;
    }
  }
  __syncthreads();
  // phase C: LN2 rows -> hi/lo
  for (int j = wv; j < 17; j += 4) {
    float v[8];
    float s = 0.0f;
#pragma unroll
    for (int i = 0; i < 8; i++) { v[i] = xs[j][ln_ + 64 * i]; s += v[i]; }
#pragma unroll
    for (int m = 32; m; m >>= 1) s += __shfl_xor(s, m);
    float mean = s * (1.0f / 512.0f);
    float s2 = 0.0f;
#pragma unroll
    for (int i = 0; i < 8; i++) { float t = v[i] - mean; s2 += t * t; }
#pragma unroll
    for (int m = 32; m; m >>= 1) s2 += __shfl_xor(s2, m);
    float rs = 1.0f / sqrtf(s2 * (1.0f / 512.0f) + 1e-5f);
#pragma unroll
    for (int i = 0; i < 8; i++) {
      int d = ln_ + 64 * i;
      float o = (v[i] - mean) * rs * g2[d] + b2[d];
      u16 h = bf16_rne(o);
      size_t off = ((size_t)b * 17 + j) * 512 + d;
      oh[off] = h;
      ol[off] = bf16_rne(o - bf16_f(h));
    }
  }
}

// ---------------- fused enc_ln + token linmix (17->34) + feat_w prep ----------------
__global__ __launch_bounds__(256) void lnmix_fused(
    const float* __restrict__ x_in, u16* __restrict__ oh, u16* __restrict__ ol,
    const float* __restrict__ g, const float* __restrict__ bb,
    const float* __restrict__ w, const float* __restrict__ bias,
    const float* __restrict__ Wf, u16* __restrict__ Thf, u16* __restrict__ Tlf) {
  __shared__ float xs[17][513];
  const int tid = threadIdx.x;
  const int b = blockIdx.x;
  {
    int gid = b * 256 + tid;
    int k = gid >> 9, n = gid & 511;
    float v = Wf[gid];
    u16 h = bf16_rne(v);
    Thf[(size_t)n * 512 + k] = h;
    Tlf[(size_t)n * 512 + k] = bf16_rne(v - bf16_f(h));
  }
  const float* px = x_in + (size_t)b * 17 * 512;
  for (int i = tid; i < 17 * 512; i += 256) xs[i >> 9][i & 511] = px[i];
  __syncthreads();
  const int wv = tid >> 6, ln_ = tid & 63;
  for (int j = wv; j < 17; j += 4) {
    float v[8];
    float s = 0.0f;
#pragma unroll
    for (int i = 0; i < 8; i++) { v[i] = xs[j][ln_ + 64 * i]; s += v[i]; }
#pragma unroll
    for (int m = 32; m; m >>= 1) s += __shfl_xor(s, m);
    float mean = s * (1.0f / 512.0f);
    float s2 = 0.0f;
#pragma unroll
    for (int i = 0; i < 8; i++) { float t = v[i] - mean; s2 += t * t; }
#pragma unroll
    for (int m = 32; m; m >>= 1) s2 += __shfl_xor(s2, m);
    float rs = 1.0f / sqrtf(s2 * (1.0f / 512.0f) + 1e-5f);
#pragma unroll
    for (int i = 0; i < 8; i++) {
      int d = ln_ + 64 * i;
      xs[j][d] = (v[i] - mean) * rs * g[d] + bb[d];
    }
  }
  __syncthreads();
  {
    const int d0 = tid, d1 = tid + 256;
    float t0[17], t1[17];
#pragma unroll
    for (int j = 0; j < 17; j++) { t0[j] = xs[j][d0]; t1[j] = xs[j][d1]; }
#pragma unroll 1
    for (int m = 0; m < 34; m++) {
      float s0 = bias[m], s1 = s0;
#pragma unroll
      for (int j = 0; j < 17; j++) {
        float wv2 = w[j * 34 + m];
        s0 = fmaf(t0[j], wv2, s0);
        s1 = fmaf(t1[j], wv2, s1);
      }
      size_t o0 = ((size_t)b * 34 + m) * 512 + d0;
      u16 h0 = bf16_rne(s0);
      oh[o0] = h0;
      ol[o0] = bf16_rne(s0 - bf16_f(h0));
      size_t o1 = o0 + 256;
      u16 h1 = bf16_rne(s1);
      oh[o1] = h1;
      ol[o1] = bf16_rne(s1 - bf16_f(h1));
    }
  }
}

// ---------------- fused codebook split + L2 norms + packed/cnt init ----------------
__global__ __launch_bounds__(256) void splitnorm_kernel(
    const float* __restrict__ CBm, u16* __restrict__ hi, u16* __restrict__ lo,
    float* __restrict__ cnorm, u64* __restrict__ packed, int* __restrict__ cnt) {
  int gid = blockIdx.x * 256 + threadIdx.x;   // 512*256 = 131072
  for (int i = gid; i < RM; i += 131072) packed[i] = ~0ull;
  if (gid < 2048) cnt[gid] = 0;
  int wave = threadIdx.x >> 6, lane = threadIdx.x & 63;
  int k = blockIdx.x * 4 + wave;
  const float4* p4 = (const float4*)(CBm + (size_t)k * 512);
  ushort4* h4 = (ushort4*)(hi + (size_t)k * 512);
  ushort4* l4 = (ushort4*)(lo + (size_t)k * 512);
  float s = 0.0f;
#pragma unroll
  for (int i = 0; i < 2; i++) {
    float4 x = p4[lane + 64 * i];
    ushort4 h, l;
    h.x = bf16_rne(x.x); l.x = bf16_rne(x.x - bf16_f(h.x));
    h.y = bf16_rne(x.y); l.y = bf16_rne(x.y - bf16_f(h.y));
    h.z = bf16_rne(x.z); l.z = bf16_rne(x.z - bf16_f(h.z));
    h.w = bf16_rne(x.w); l.w = bf16_rne(x.w - bf16_f(h.w));
    h4[lane + 64 * i] = h;
    l4[lane + 64 * i] = l;
    s = fmaf(x.x, x.x, s); s = fmaf(x.y, x.y, s);
    s = fmaf(x.z, x.z, s); s = fmaf(x.w, x.w, s);
  }
#pragma unroll
  for (int m = 32; m; m >>= 1) s += __shfl_xor(s, m);
  if (lane == 0) cnorm[k] = s;
}

// ---------------- split-bf16 MFMA GEMM, 64x128 tile ----------------
template <int GELU_FLAG, int RES_FLAG, int HILO_OUT>
__global__ __launch_bounds__(256, 4) void mgemm64(
    const u16* __restrict__ Ah, const u16* __restrict__ Al,
    const u16* __restrict__ Bh, const u16* __restrict__ Bl,
    const float* __restrict__ bias, const float* __restrict__ R,
    float* __restrict__ C, u16* __restrict__ Oh, u16* __restrict__ Ol, int N) {
  __shared__ __align__(16) u16 sAh[2048], sAl[2048], sBh[4096], sBl[4096];
  const int tid = threadIdx.x;
  const int m0 = blockIdx.x * 64, n0 = blockIdx.y * 128;
  const int lane = tid & 63, wave = tid >> 6;
  const int wm = wave >> 1, wn = wave & 1;
  const int fr = lane & 15, q = lane >> 4;
  const int ra = tid >> 2, ca = (tid & 3) ^ ((ra >> 1) & 3);
  const size_t aoff = (size_t)(m0 + ra) * 512 + ca * 8;
  const int rb0 = tid >> 2, cb0 = (tid & 3) ^ ((rb0 >> 1) & 3);
  const int ci1 = tid + 256;
  const int rb1 = ci1 >> 2, cb1 = (ci1 & 3) ^ ((rb1 >> 1) & 3);
  const size_t boff0 = (size_t)(n0 + rb0) * 512 + cb0 * 8;
  const size_t boff1 = (size_t)(n0 + rb1) * 512 + cb1 * 8;
  const int ldA = wave * 512;
  const int ldB0 = wave * 512, ldB1 = 2048 + wave * 512;
  int fca[2], fcb[4];
#pragma unroll
  for (int mt = 0; mt < 2; mt++) {
    int rra = wm * 32 + mt * 16 + fr;
    fca[mt] = (rra * 4 + (q ^ ((rra >> 1) & 3))) * 8;
  }
#pragma unroll
  for (int nt = 0; nt < 4; nt++) {
    int rrb = wn * 64 + nt * 16 + fr;
    fcb[nt] = (rrb * 4 + (q ^ ((rrb >> 1) & 3))) * 8;
  }
  f32x4 acc[2][4];
#pragma unroll
  for (int i = 0; i < 2; i++)
#pragma unroll
    for (int j = 0; j < 4; j++) {
      acc[i][j][0] = 0.0f; acc[i][j][1] = 0.0f;
      acc[i][j][2] = 0.0f; acc[i][j][3] = 0.0f;
    }
  for (int k0 = 0; k0 < 512; k0 += 32) {
    gll16(Ah + aoff + k0, &sAh[ldA]);
    gll16(Al + aoff + k0, &sAl[ldA]);
    gll16(Bh + boff0 + k0, &sBh[ldB0]);
    gll16(Bh + boff1 + k0, &sBh[ldB1]);
    gll16(Bl + boff0 + k0, &sBl[ldB0]);
    gll16(Bl + boff1 + k0, &sBl[ldB1]);
    __syncthreads();
    bf16x8 fah[2], fal[2], fbh[4], fbl[4];
#pragma unroll
    for (int mt = 0; mt < 2; mt++) {
      fah[mt] = *(const bf16x8*)&sAh[fca[mt]];
      fal[mt] = *(const bf16x8*)&sAl[fca[mt]];
    }
#pragma unroll
    for (int nt = 0; nt < 4; nt++) {
      fbh[nt] = *(const bf16x8*)&sBh[fcb[nt]];
      fbl[nt] = *(const bf16x8*)&sBl[fcb[nt]];
    }
#pragma unroll
    for (int mt = 0; mt < 2; mt++)
#pragma unroll
      for (int nt = 0; nt < 4; nt++) {
        acc[mt][nt] = __builtin_amdgcn_mfma_f32_16x16x32_bf16(
            fah[mt], fbh[nt], acc[mt][nt], 0, 0, 0);
        acc[mt][nt] = __builtin_amdgcn_mfma_f32_16x16x32_bf16(
            fah[mt], fbl[nt], acc[mt][nt], 0, 0, 0);
        acc[mt][nt] = __builtin_amdgcn_mfma_f32_16x16x32_bf16(
            fal[mt], fbh[nt], acc[mt][nt], 0, 0, 0);
      }
    __syncthreads();
  }
#pragma unroll
  for (int mt = 0; mt < 2; mt++)
#pragma unroll
    for (int reg = 0; reg < 4; reg++) {
      int row = m0 + wm * 32 + mt * 16 + q * 4 + reg;
#pragma unroll
      for (int nt = 0; nt < 4; nt++) {
        int col = n0 + wn * 64 + nt * 16 + fr;
        float v = acc[mt][nt][reg] + bias[col];
        if (GELU_FLAG) v = gelu_f(v);
        if (RES_FLAG) v += R[(size_t)row * N + col];
        if (HILO_OUT) {
          u16 h = bf16_rne(v);
          Oh[(size_t)row * N + col] = h;
          Ol[(size_t)row * N + col] = bf16_rne(v - bf16_f(h));
        } else {
          C[(size_t)row * N + col] = v;
        }
      }
    }
}

// ======== M=128 staging/compute macros (dist kernel, validated) ========
#define MG_PROLOGUE()                                                        \
  const int tid = threadIdx.x;                                               \
  const int m0 = blockIdx.x * 128, n0 = (blockIdx.y + n_base) * 128;         \
  const int lane = tid & 63, wave = tid >> 6;                                \
  const int wm = wave >> 1, wn = wave & 1;                                   \
  const int fr = lane & 15, q = lane >> 4, qd = q;                           \
  const int ci0 = wave * 128 + lane, ci1 = ci0 + 64;                         \
  const int r0 = ci0 >> 2, c0x = (ci0 & 3) ^ ((r0 >> 1) & 3);                \
  const int r1 = ci1 >> 2, c1x = (ci1 & 3) ^ ((r1 >> 1) & 3);                \
  const size_t aoff0 = (size_t)(m0 + r0) * 512 + c0x * 8;                    \
  const size_t aoff1 = (size_t)(m0 + r1) * 512 + c1x * 8;                    \
  const size_t boff0 = (size_t)(n0 + r0) * 512 + c0x * 8;                    \
  const size_t boff1 = (size_t)(n0 + r1) * 512 + c1x * 8;                    \
  const int ld0 = wave * 1024, ld1 = ld0 + 512; /* u16 index of dest */      \
  int fca[4], fcb[4];                                                        \
  _Pragma("unroll") for (int t4 = 0; t4 < 4; t4++) {                         \
    int rra = wm * 64 + t4 * 16 + fr;                                        \
    int rrb = wn * 64 + t4 * 16 + fr;                                        \
    int sz = q ^ ((fr >> 1) & 3);                                            \
    fca[t4] = (rra * 4 + sz) * 8;                                            \
    fcb[t4] = (rrb * 4 + sz) * 8;                                            \
  }                                                                          \
  f32x4 acc[4][4];                                                           \
  _Pragma("unroll") for (int i = 0; i < 4; i++)                              \
    _Pragma("unroll") for (int j = 0; j < 4; j++) {                          \
      acc[i][j][0] = 0.0f; acc[i][j][1] = 0.0f;                              \
      acc[i][j][2] = 0.0f; acc[i][j][3] = 0.0f;                              \
    }

#define MG_KLOOP(Ah, Al, Bh, Bl)                                             \
  for (int k0 = 0; k0 < 512; k0 += 32) {                                     \
    gll16(Ah + aoff0 + k0, &sAh[ld0]);                                       \
    gll16(Ah + aoff1 + k0, &sAh[ld1]);                                       \
    gll16(Al + aoff0 + k0, &sAl[ld0]);                                       \
    gll16(Al + aoff1 + k0, &sAl[ld1]);                                       \
    gll16(Bh + boff0 + k0, &sBh[ld0]);                                       \
    gll16(Bh + boff1 + k0, &sBh[ld1]);                                       \
    gll16(Bl + boff0 + k0, &sBl[ld0]);                                       \
    gll16(Bl + boff1 + k0, &sBl[ld1]);                                       \
    __syncthreads();                                                         \
    bf16x8 fah[4], fal[4], fbh[4], fbl[4];                                   \
    _Pragma("unroll") for (int t4 = 0; t4 < 4; t4++) {                       \
      fah[t4] = *(const bf16x8*)&sAh[fca[t4]];                               \
      fal[t4] = *(const bf16x8*)&sAl[fca[t4]];                               \
      fbh[t4] = *(const bf16x8*)&sBh[fcb[t4]];                               \
      fbl[t4] = *(const bf16x8*)&sBl[fcb[t4]];                               \
    }                                                                        \
    _Pragma("unroll") for (int mt = 0; mt < 4; mt++)                         \
      _Pragma("unroll") for (int nt = 0; nt < 4; nt++) {                     \
        acc[mt][nt] = __builtin_amdgcn_mfma_f32_16x16x32_bf16(               \
            fah[mt], fbh[nt], acc[mt][nt], 0, 0, 0);                         \
        acc[mt][nt] = __builtin_amdgcn_mfma_f32_16x16x32_bf16(               \
            fah[mt], fbl[nt], acc[mt][nt], 0, 0, 0);                         \
        acc[mt][nt] = __builtin_amdgcn_mfma_f32_16x16x32_bf16(               \
            fal[mt], fbh[nt], acc[mt][nt], 0, 0, 0);                         \
      }                                                                      \
    __syncthreads();                                                         \
  }

// ---------------- distance GEMM + packed-u64 argmin (half-grid, n_base) ----------------
__global__ __launch_bounds__(256, 5) void dist_mfma(
    const u16* __restrict__ Ah, const u16* __restrict__ Al,
    const u16* __restrict__ Bh, const u16* __restrict__ Bl,
    const float* __restrict__ cnorm, u64* __restrict__ packed, int n_base) {
  __shared__ __align__(16) u16 sAh[4096], sAl[4096], sBh[4096], sBl[4096];
  MG_PROLOGUE()
  MG_KLOOP(Ah, Al, Bh, Bl)
#pragma unroll
  for (int mt = 0; mt < 4; mt++)
#pragma unroll
    for (int reg = 0; reg < 4; reg++) {
      u64 best = ~0ull;
#pragma unroll
      for (int nt = 0; nt < 4; nt++) {
        int c = n0 + wn * 64 + nt * 16 + fr;
        float d = cnorm[c] - 2.0f * acc[mt][nt][reg];
        u32 ub = __float_as_uint(d);
        ub = (ub & 0x80000000u) ? ~ub : (ub | 0x80000000u);
        u64 p = ((u64)ub << 32) | (u32)c;
        best = (p < best) ? p : best;
      }
#pragma unroll
      for (int mm = 1; mm <= 8; mm <<= 1) {
        u32 h2 = __shfl_xor((u32)(best >> 32), mm);
        u32 l2 = __shfl_xor((u32)best, mm);
        u64 o = ((u64)h2 << 32) | l2;
        best = (o < best) ? o : best;
      }
      if (fr == 0) {
        int row = m0 + wm * 64 + mt * 16 + qd * 4 + reg;
        atomicMin(&packed[row], best);
      }
    }
}

// ---------------- idx output + skew-oblivious count (fused) ----------------
__global__ __launch_bounds__(256) void idxcount_kernel(
    const u64* __restrict__ packed, float* __restrict__ o_idx,
    int* __restrict__ cnt) {
  __shared__ int h[2048];
  for (int i = threadIdx.x; i < 2048; i += 256) h[i] = 0;
  __syncthreads();
  int r = blockIdx.x * 256 + threadIdx.x;
  u32 k = (u32)packed[r];
  o_idx[r] = (float)k;
  atomicAdd(&h[k], 1);
  __syncthreads();
  for (int i = threadIdx.x; i < 2048; i += 256) {
    int v = h[i];
    if (v) atomicAdd(&cnt[i], v);
  }
}

__global__ __launch_bounds__(256) void scan_kernel(
    const int* __restrict__ cnt, int* __restrict__ base,
    int* __restrict__ cursor, const float* __restrict__ ema_cs,
    float* __restrict__ nbuf) {
  __shared__ int part[256];
  __shared__ float esum[256];
  int t = threadIdx.x;
  int local[8];
  int s = 0;
  float es = 0.0f;
#pragma unroll
  for (int i = 0; i < 8; i++) {
    local[i] = cnt[t * 8 + i];
    s += local[i];
    es += ema_cs[t * 8 + i];
  }
  part[t] = s;
  esum[t] = es;
  __syncthreads();
  for (int off = 1; off < 256; off <<= 1) {
    int v = (t >= off) ? part[t - off] : 0;
    __syncthreads();
    part[t] += v;
    __syncthreads();
  }
  int run = part[t] - s;
#pragma unroll
  for (int i = 0; i < 8; i++) {
    base[t * 8 + i] = run;
    cursor[t * 8 + i] = run;
    run += local[i];
  }
  for (int o = 128; o; o >>= 1) {
    if (t < o) esum[t] += esum[t + o];
    __syncthreads();
  }
  if (t == 0) nbuf[0] = 0.9f * esum[0] + 0.1f * (float)RM;
}

// ---------------- scatter (+ fused dw zeroing; WT dead by now) ----------------
__global__ __launch_bounds__(256) void scatter_kernel(
    const u64* __restrict__ packed, int* __restrict__ cursor,
    u32* __restrict__ bucket, float* __restrict__ dw) {
  __shared__ int h[2048];
  __shared__ int gb[2048];
  int gid = blockIdx.x * 256 + threadIdx.x;   // 34816 threads
  for (int i = gid; i < 2048 * 512; i += RM) dw[i] = 0.0f;
  for (int i = threadIdx.x; i < 2048; i += 256) h[i] = 0;
  __syncthreads();
  int k = (int)(u32)packed[gid];
  int lrank = atomicAdd(&h[k], 1);
  __syncthreads();
  for (int i = threadIdx.x; i < 2048; i += 256) {
    int v = h[i];
    gb[i] = v ? atomicAdd(&cursor[i], v) : 0;
  }
  __syncthreads();
  bucket[gb[k] + lrank] = ((u32)k << 17) | (u32)gid;
}

// ---------------- dw segment-sum + quant gather (ptf) + loss partials, merged ----------------
// thread t owns dims (2t, 2t+1) of every row in its 64-row bucket chunk.
__global__ __launch_bounds__(256) void dwsum_chunk_kernel(
    const u16* __restrict__ fh, const u16* __restrict__ fl,
    const u32* __restrict__ bucket, const float* __restrict__ CBm,
    float* __restrict__ dw, float* __restrict__ ptf_out,
    float* __restrict__ lpart) {
  __shared__ u32 sp[64];
  __shared__ float wred[4];
  const int t = threadIdx.x;
  if (t < 64) sp[t] = bucket[blockIdx.x * 64 + t];
  __syncthreads();
  float ax = 0.0f, ay = 0.0f, lacc = 0.0f;
  int curk = (int)(sp[0] >> 17);
  float c0 = CBm[(size_t)curk * 512 + 2 * t];
  float c1 = CBm[(size_t)curk * 512 + 2 * t + 1];
  u32 hb = *(const u32*)(fh + (size_t)(sp[0] & 0x1FFFF) * 512 + 2 * t);
  u32 lb = *(const u32*)(fl + (size_t)(sp[0] & 0x1FFFF) * 512 + 2 * t);
  for (int i = 0; i < 64; i++) {
    u32 hn = 0, ln2 = 0;
    if (i + 1 < 64) {
      hn = *(const u32*)(fh + (size_t)(sp[i + 1] & 0x1FFFF) * 512 + 2 * t);
      ln2 = *(const u32*)(fl + (size_t)(sp[i + 1] & 0x1FFFF) * 512 + 2 * t);
    }
    int k = (int)(sp[i] >> 17);
    if (k != curk) {
      atomicAdd(&dw[(size_t)curk * 512 + 2 * t], ax);
      atomicAdd(&dw[(size_t)curk * 512 + 2 * t + 1], ay);
      ax = 0.0f; ay = 0.0f; curk = k;
      c0 = CBm[(size_t)k * 512 + 2 * t];
      c1 = CBm[(size_t)k * 512 + 2 * t + 1];
    }
    float f0 = bf16_f((u16)hb) + bf16_f((u16)lb);
    float f1 = bf16_f((u16)(hb >> 16)) + bf16_f((u16)(lb >> 16));
    ax += f0;
    ay += f1;
    int row = (int)(sp[i] & 0x1FFFF);
    ptf_out[(size_t)row * 512 + 2 * t] = c0;
    ptf_out[(size_t)row * 512 + 2 * t + 1] = c1;
    float e0 = c0 - f0, e1 = c1 - f1;
    lacc = fmaf(e0, e0, fmaf(e1, e1, lacc));
    hb = hn; lb = ln2;
  }
  atomicAdd(&dw[(size_t)curk * 512 + 2 * t], ax);
  atomicAdd(&dw[(size_t)curk * 512 + 2 * t + 1], ay);
#pragma unroll
  for (int m = 32; m; m >>= 1) lacc += __shfl_xor(lacc, m);
  if ((t & 63) == 0) wred[t >> 6] = lacc;
  __syncthreads();
  if (t == 0) lpart[blockIdx.x] = wred[0] + wred[1] + wred[2] + wred[3];
}

// ---------------- codebook_new finalize (+ fused loss reduction in block 0) ----------------
__global__ __launch_bounds__(256) void cbnew_kernel(
    const float* __restrict__ ema_w, const float* __restrict__ dw,
    const float* __restrict__ ema_cs, const int* __restrict__ cnt,
    const float* __restrict__ nbuf, float* __restrict__ outp,
    const float* __restrict__ lpart, float* __restrict__ loss_out) {
  int tid = blockIdx.x * 256 + threadIdx.x;
  int k = tid >> 9;
  float n = nbuf[0];
  float cs = ema_cs[k] * 0.9f + 0.1f * (float)cnt[k];
  cs = (cs + 1e-5f) / (n + 0.02048f) * n;
  outp[tid] = (ema_w[tid] * 0.9f + 0.1f * dw[tid]) / cs;
  if (blockIdx.x == 0) {
    __shared__ float red[256];
    float s = 0.0f;
    for (int i = threadIdx.x; i < RM / 64; i += 256) s += lpart[i];
    red[threadIdx.x] = s;
    __syncthreads();
    for (int o = 128; o; o >>= 1) {
      if (threadIdx.x < o) red[threadIdx.x] += red[threadIdx.x + o];
      __syncthreads();
    }
    if (threadIdx.x == 0)
      loss_out[0] = red[0] / (float)((size_t)RM * 512);
  }
}

// ---------------- fully fused decoder: one block per pose ----------------
__global__ __launch_bounds__(256) void decoder_fused(
    const float* __restrict__ ptf,
    const float* __restrict__ dtokw, const float* __restrict__ dtokb,
    const float* __restrict__ dsw, const float* __restrict__ dsb,
    const float* __restrict__ ln1g, const float* __restrict__ ln1b,
    const float* __restrict__ tw1, const float* __restrict__ tb1,
    const float* __restrict__ tw2, const float* __restrict__ tb2,
    const float* __restrict__ ln2g, const float* __restrict__ ln2b,
    const float* __restrict__ cw1, const float* __restrict__ cb1,
    const float* __restrict__ cw2, const float* __restrict__ cb2,
    const float* __restrict__ lng, const float* __restrict__ lnb,
    const float* __restrict__ recw, const float* __restrict__ recb,
    float* __restrict__ o_rec) {
  __shared__ float yS[17][260];
  __shared__ float zS[17][33];
  __shared__ float t2S[17][33];
  __shared__ float hS[17][65];
  const int tid = threadIdx.x;
  const int b = blockIdx.x;
  float zacc0 = 0.0f, zacc1 = 0.0f, zacc2 = 0.0f;
  const int j0 = tid >> 5, dd0 = tid & 31;
  const int j1 = (tid + 256) >> 5;
  const int j2 = (tid + 512) >> 5;           // valid iff tid < 32
  for (int ch = 0; ch < 2; ch++) {
    float p[34];
#pragma unroll
    for (int m = 0; m < 34; m++)
      p[m] = ptf[((size_t)b * 34 + m) * 512 + ch * 256 + tid];
#pragma unroll 1
    for (int j = 0; j < 17; j++) {
      float s = dtokb[j];
#pragma unroll
      for (int m = 0; m < 34; m++) s = fmaf(p[m], dtokw[m * 17 + j], s);
      yS[j][tid] = s;
    }
    __syncthreads();
    {
      const float4* y0 = (const float4*)&yS[j0][0];
      const float4* y1 = (const float4*)&yS[j1][0];
      const float* wg = dsw + (size_t)ch * 256 * 32 + dd0;
#pragma unroll 1
      for (int d4 = 0; d4 < 64; d4++) {
        float4 va = y0[d4];
        float4 vb = y1[d4];
        float w0 = wg[(4 * d4 + 0) * 32];
        float w1 = wg[(4 * d4 + 1) * 32];
        float w2 = wg[(4 * d4 + 2) * 32];
        float w3 = wg[(4 * d4 + 3) * 32];
        zacc0 = fmaf(va.x, w0, zacc0); zacc0 = fmaf(va.y, w1, zacc0);
        zacc0 = fmaf(va.z, w2, zacc0); zacc0 = fmaf(va.w, w3, zacc0);
        zacc1 = fmaf(vb.x, w0, zacc1); zacc1 = fmaf(vb.y, w1, zacc1);
        zacc1 = fmaf(vb.z, w2, zacc1); zacc1 = fmaf(vb.w, w3, zacc1);
      }
      if (tid < 32) {
        const float4* y2 = (const float4*)&yS[j2][0];
#pragma unroll 1
        for (int d4 = 0; d4 < 64; d4++) {
          float4 vc = y2[d4];
          float w0 = wg[(4 * d4 + 0) * 32];
          float w1 = wg[(4 * d4 + 1) * 32];
          float w2 = wg[(4 * d4 + 2) * 32];
          float w3 = wg[(4 * d4 + 3) * 32];
          zacc2 = fmaf(vc.x, w0, zacc2); zacc2 = fmaf(vc.y, w1, zacc2);
          zacc2 = fmaf(vc.z, w2, zacc2); zacc2 = fmaf(vc.w, w3, zacc2);
        }
      }
    }
    __syncthreads();
  }
  zS[j0][dd0] = zacc0 + dsb[dd0];
  zS[j1][dd0] = zacc1 + dsb[dd0];
  if (tid < 32) zS[j2][dd0] = zacc2 + dsb[dd0];
  __syncthreads();
  if (tid < 17) {
    float m = 0.0f;
#pragma unroll
    for (int d = 0; d < 32; d++) m += zS[tid][d];
    m *= (1.0f / 32.0f);
    float v = 0.0f;
#pragma unroll
    for (int d = 0; d < 32; d++) { float t = zS[tid][d] - m; v += t * t; }
    float rs = 1.0f / sqrtf(v * (1.0f / 32.0f) + 1e-5f);
#pragma unroll
    for (int d = 0; d < 32; d++)
      t2S[tid][d] = (zS[tid][d] - m) * rs * ln1g[d] + ln1b[d];
  }
  __syncthreads();
  if (tid < 32) {
    float t[17], acc[17];
#pragma unroll
    for (int j = 0; j < 17; j++) { t[j] = t2S[j][tid]; acc[j] = 0.0f; }
    for (int k = 0; k < 64; k++) {
      float h = tb1[k];
#pragma unroll
      for (int j = 0; j < 17; j++) h = fmaf(t[j], tw1[j * 64 + k], h);
      h = gelu_f(h);
#pragma unroll
      for (int j = 0; j < 17; j++) acc[j] = fmaf(h, tw2[k * 17 + j], acc[j]);
    }
#pragma unroll
    for (int j = 0; j < 17; j++) zS[j][tid] = zS[j][tid] + acc[j] + tb2[j];
  }
  __syncthreads();
  if (tid < 17) {
    float m = 0.0f;
#pragma unroll
    for (int d = 0; d < 32; d++) m += zS[tid][d];
    m *= (1.0f / 32.0f);
    float v = 0.0f;
#pragma unroll
    for (int d = 0; d < 32; d++) { float t = zS[tid][d] - m; v += t * t; }
    float rs = 1.0f / sqrtf(v * (1.0f / 32.0f) + 1e-5f);
#pragma unroll
    for (int d = 0; d < 32; d++)
      t2S[tid][d] = (zS[tid][d] - m) * rs * ln2g[d] + ln2b[d];
  }
  __syncthreads();
  for (int p = tid; p < 17 * 64; p += 256) {
    int j = p >> 6, k = p & 63;
    float s = cb1[k];
#pragma unroll
    for (int d = 0; d < 32; d++) s = fmaf(t2S[j][d], cw1[d * 64 + k], s);
    hS[j][k] = gelu_f(s);
  }
  __syncthreads();
  {
    float cb = cb2[dd0];
    float s0 = cb, s1 = cb;
#pragma unroll
    for (int k = 0; k < 64; k++) {
      float w = cw2[k * 32 + dd0];
      s0 = fmaf(hS[j0][k], w, s0);
      s1 = fmaf(hS[j1][k], w, s1);
    }
    zS[j0][dd0] += s0;
    zS[j1][dd0] += s1;
    if (tid < 32) {
      float s2 = cb;
#pragma unroll
      for (int k = 0; k < 64; k++) s2 = fmaf(hS[j2][k], cw2[k * 32 + dd0], s2);
      zS[j2][dd0] += s2;
    }
  }
  __syncthreads();
  if (tid < 17) {
    float m = 0.0f;
#pragma unroll
    for (int d = 0; d < 32; d++) m += zS[tid][d];
    m *= (1.0f / 32.0f);
    float v = 0.0f;
#pragma unroll
    for (int d = 0; d < 32; d++) { float t = zS[tid][d] - m; v += t * t; }
    float rs = 1.0f / sqrtf(v * (1.0f / 32.0f) + 1e-5f);
#pragma unroll
    for (int d = 0; d < 32; d++)
      t2S[tid][d] = (zS[tid][d] - m) * rs * lng[d] + lnb[d];
  }
  __syncthreads();
  if (tid < 34) {
    int j = tid >> 1, c = tid & 1;
    float s = recb[c];
#pragma unroll
    for (int d = 0; d < 32; d++) s = fmaf(t2S[j][d], recw[d * 2 + c], s);
    o_rec[((size_t)b * 17 + j) * 2 + c] = s;
  }
}

// ================================================================
extern "C" void kernel_launch(void* const* d_in, const int* in_sizes, int n_in,
                              void* d_out, int out_size, void* d_ws, size_t ws_size,
                              hipStream_t stream) {
  const float* joints   = (const float*)d_in[0];
  const float* inv_tok  = (const float*)d_in[3];
  const float* start_w  = (const float*)d_in[4];
  const float* start_b  = (const float*)d_in[5];
  const float* e_ln1g = (const float*)d_in[6];
  const float* e_ln1b = (const float*)d_in[7];
  const float* e_tw1  = (const float*)d_in[8];
  const float* e_tb1  = (const float*)d_in[9];
  const float* e_tw2  = (const float*)d_in[10];
  const float* e_tb2  = (const float*)d_in[11];
  const float* e_ln2g = (const float*)d_in[12];
  const float* e_ln2b = (const float*)d_in[13];
  const float* e_cw1  = (const float*)d_in[14];
  const float* e_cb1  = (const float*)d_in[15];
  const float* e_cw2  = (const float*)d_in[16];
  const float* e_cb2  = (const float*)d_in[17];
  const float* d_ln1g = (const float*)d_in[18];
  const float* d_ln1b = (const float*)d_in[19];
  const float* d_tw1  = (const float*)d_in[20];
  const float* d_tb1  = (const float*)d_in[21];
  const float* d_tw2  = (const float*)d_in[22];
  const float* d_tb2  = (const float*)d_in[23];
  const float* d_ln2g = (const float*)d_in[24];
  const float* d_ln2b = (const float*)d_in[25];
  const float* d_cw1  = (const float*)d_in[26];
  const float* d_cb1  = (const float*)d_in[27];
  const float* d_cw2  = (const float*)d_in[28];
  const float* d_cb2  = (const float*)d_in[29];
  const float* enc_lng = (const float*)d_in[30];
  const float* enc_lnb = (const float*)d_in[31];
  const float* tok_w   = (const float*)d_in[32];
  const float* tok_b   = (const float*)d_in[33];
  const float* feat_w  = (const float*)d_in[34];
  const float* feat_b  = (const float*)d_in[35];
  const float* codebook = (const float*)d_in[36];
  const float* ema_cs   = (const float*)d_in[37];
  const float* ema_w    = (const float*)d_in[38];
  const float* dtok_w   = (const float*)d_in[39];
  const float* dtok_b   = (const float*)d_in[40];
  const float* dstart_w = (const float*)d_in[41];
  const float* dstart_b = (const float*)d_in[42];
  const float* dec_lng  = (const float*)d_in[43];
  const float* dec_lnb  = (const float*)d_in[44];
  const float* rec_w    = (const float*)d_in[45];
  const float* rec_b    = (const float*)d_in[46];

  // -------- workspace layout (same proven footprint) --------
  float* ws = (float*)d_ws;
  float* Ab  = ws;                  // [RJ,512] fp32 residual
  float* Bb  = ws + SZX;            // [RJ,512] fp32 (x+y residual)
  float* Cc  = ws + 2 * SZX;        // scratch
  float* P1e = ws + 3 * SZX;        // RJ bf16 hi+lo (ln2 out)
  float* P2e = ws + 4 * SZX;        // RJ bf16 hi+lo (mgemm1 out)
  float* cbs = ws + 5 * SZX;        // codebook split hi+lo
  float* cnorm = cbs + 1048576;                      // 2048
  u64*  packed = (u64*)(cnorm + 2048);               // RM u64
  int*  cnt    = (int*)(cnorm + 2048 + 69632);       // 2048
  int*  basebuf = cnt + 2048;
  int*  cursor  = basebuf + 2048;
  u32*  bucket  = (u32*)(cursor + 2048);             // RM
  float* lpart  = (float*)(bucket + RM);             // RM/64
  float* nbuf   = lpart + RM / 2;                    // 1 (padded)
  float* dw     = nbuf + 2048;                       // 2048*512
  u16* WTh1 = (u16*)dw;
  u16* WTl1 = (u16*)(dw + 131072);
  u16* WTh2 = (u16*)(dw + 262144);
  u16* WTl2 = (u16*)(dw + 393216);
  u16* P1eh = (u16*)P1e;  u16* P1el = (u16*)(P1e + SZX / 2);
  u16* P2eh = (u16*)P2e;  u16* P2el = (u16*)(P2e + SZX / 2);
  u16* P1mh = (u16*)Ab;   u16* P1ml = (u16*)Bb;
  u16* P2mh = (u16*)Cc;   u16* P2ml = (u16*)P1e;
  u16* chh = (u16*)cbs;   u16* cll = (u16*)(cbs + 524288);

  // -------- outputs --------
  float* outp = (float*)d_out;
  float* o_rec = outp;
  float* o_idx = outp + (size_t)RJ * 2;
  float* o_loss = o_idx + RM;
  float* o_ptf = o_loss + 1;
  float* o_cb = o_ptf + SZM;

  // -------- encoder (embed fused into layer-0 mixer) --------
  for (int i = 0; i < 4; i++) {
    if (i == 0) {
      mixer_fused<1><<<Bn, 256, 0, stream>>>(
          nullptr, Bb, P1eh, P1el,
          e_ln1g, e_ln1b, e_tw1, e_tb1, e_tw2, e_tb2, e_ln2g, e_ln2b,
          e_cw1, e_cw2, WTh1, WTl1, WTh2, WTl2,
          joints, inv_tok, start_w, start_b);
    } else {
      mixer_fused<0><<<Bn, 256, 0, stream>>>(
          Ab, Bb, P1eh, P1el,
          e_ln1g + i * 512, e_ln1b + i * 512,
          e_tw1 + i * 17 * 64, e_tb1 + i * 64, e_tw2 + i * 64 * 17, e_tb2 + i * 17,
          e_ln2g + i * 512, e_ln2b + i * 512,
          e_cw1 + (size_t)i * 512 * 512, e_cw2 + (size_t)i * 512 * 512,
          WTh1, WTl1, WTh2, WTl2, nullptr, nullptr, nullptr, nullptr);
    }
    mgemm64<1, 0, 1><<<dim3(RJ / 64, 4), 256, 0, stream>>>(
        P1eh, P1el, WTh1, WTl1, e_cb1 + i * 512, nullptr, nullptr, P2eh, P2el, 512);
    mgemm64<0, 1, 0><<<dim3(RJ / 64, 4), 256, 0, stream>>>(
        P2eh, P2el, WTh2, WTl2, e_cb2 + i * 512, Bb, Ab, nullptr, nullptr, 512);
  }
  lnmix_fused<<<Bn, 256, 0, stream>>>(Ab, P1mh, P1ml, enc_lng, enc_lnb, tok_w, tok_b,
                                      feat_w, WTh1, WTl1);
  mgemm64<0, 0, 1><<<dim3(RM / 64, 4), 256, 0, stream>>>(
      P1mh, P1ml, WTh1, WTl1, feat_b, nullptr, nullptr, P2mh, P2ml, 512);

  // -------- VQ: distances + argmin (two half-grids: diagnostic split) --------
  splitnorm_kernel<<<2048 / 4, 256, 0, stream>>>(codebook, chh, cll, cnorm, packed, cnt);
  dist_mfma<<<dim3(RM / 128, 8), 256, 0, stream>>>(P2mh, P2ml, chh, cll, cnorm, packed, 0);
  dist_mfma<<<dim3(RM / 128, 8), 256, 0, stream>>>(P2mh, P2ml, chh, cll, cnorm, packed, 8);

  // -------- skew-oblivious bucketed EMA update --------
  idxcount_kernel<<<RM / 256, 256, 0, stream>>>(packed, o_idx, cnt);
  scan_kernel<<<1, 256, 0, stream>>>(cnt, basebuf, cursor, ema_cs, nbuf);
  scatter_kernel<<<RM / 256, 256, 0, stream>>>(packed, cursor, bucket, dw);
  dwsum_chunk_kernel<<<RM / 64, 256, 0, stream>>>(
      P2mh, P2ml, bucket, codebook, dw, o_ptf, lpart);
  cbnew_kernel<<<(2048 * 512) / 256, 256, 0, stream>>>(
      ema_w, dw, ema_cs, cnt, nbuf, o_cb, lpart, o_loss);

  // -------- decoder (single fused kernel) --------
  decoder_fused<<<Bn, 256, 0, stream>>>(
      o_ptf, dtok_w, dtok_b, dstart_w, dstart_b,
      d_ln1g, d_ln1b, d_tw1, d_tb1, d_tw2, d_tb2, d_ln2g, d_ln2b,
      d_cw1, d_cb1, d_cw2, d_cb2, dec_lng, dec_lnb, rec_w, rec_b, o_rec);
}